// Round 4
// baseline (111.354 us; speedup 1.0000x reference)
//
#include <hip/hip_runtime.h>

constexpr int CN   = 32;
constexpr int CIN  = 64;
constexpr int CH   = 128;
constexpr int CW   = 128;
constexpr int COUT = 128;
constexpr int OHh  = 126;
constexpr int OWw  = 126;
constexpr int KTOT = 576;

typedef __attribute__((ext_vector_type(8))) short bf16x8;
typedef __attribute__((ext_vector_type(4))) float f32x4;

__device__ __forceinline__ unsigned short f2bf(float f) {
  union { float f; unsigned u; } v; v.f = f;
  unsigned u = v.u;
  u += 0x7FFFu + ((u >> 16) & 1u);   // RNE
  return (unsigned short)(u >> 16);
}

__device__ __forceinline__ void gload_lds16(const unsigned short* g, unsigned short* l) {
  __builtin_amdgcn_global_load_lds(
      (const __attribute__((address_space(1))) unsigned int*)g,
      (__attribute__((address_space(3))) unsigned int*)l, 16, 0, 0);
}

// ---- prep: x (N,Ci,H,W) fp32 -> xt[n][h][c][ci] bf16, T2 swizzle baked --------------
// Within each 32-ci half, logical octet o stored at slot o ^ ((c>>1)&3).
__global__ __launch_bounds__(256) void prep_xt_kernel(const float* __restrict__ x,
                                                      unsigned short* __restrict__ xt) {
  __shared__ __align__(16) unsigned short s[128][72];
  const int b = blockIdx.x;            // n*128 + h
  const int n = b >> 7, h = b & 127;
  const float* src = x + (size_t)n * CIN * CH * CW + (size_t)h * CW;
  const int t = threadIdx.x;
  #pragma unroll
  for (int r = 0; r < 8; ++r) {
    int idx = r * 256 + t;
    int ci = idx >> 5, c0 = (idx & 31) << 2;
    float4 v = *(const float4*)(src + (size_t)ci * (CH * CW) + c0);
    s[c0 + 0][ci] = f2bf(v.x);
    s[c0 + 1][ci] = f2bf(v.y);
    s[c0 + 2][ci] = f2bf(v.z);
    s[c0 + 3][ci] = f2bf(v.w);
  }
  __syncthreads();
  unsigned short* dst = xt + (size_t)b * 8192;
  #pragma unroll
  for (int r = 0; r < 4; ++r) {
    int idx = r * 256 + t;
    int c = idx >> 3, sl = idx & 7;
    int half = sl >> 2, q = sl & 3;
    int lo = q ^ ((c >> 1) & 3);
    uint4 v = *(const uint4*)&s[c][half * 32 + lo * 8];
    *(uint4*)(dst + (size_t)c * 64 + sl * 8) = v;
  }
}

// ---- prep: W -> wt[co][kw*192 + kh*64 + half*32 + slot*8 + j], swizzle baked --------
__global__ void prep_wt2_kernel(const float* __restrict__ w,
                                unsigned short* __restrict__ wt) {
  int i = blockIdx.x * 256 + threadIdx.x;
  if (i >= COUT * KTOT) return;
  int co = i / KTOT, k = i - co * KTOT;
  int kw = k / 192, r = k - kw * 192;
  int kh = r >> 6, q = r & 63;
  int half = q >> 5, qq = q & 31;
  int sl = qq >> 3, j = qq & 7;
  int o = sl ^ ((co >> 1) & 3);
  int ci = half * 32 + o * 8 + j;
  wt[i] = f2bf(w[co * 576 + ci * 9 + kh * 3 + kw]);
}

// ---- main: 512 thr, 8 waves (2co x 4px-rows), 18-phase schedule ---------------------
__global__ __launch_bounds__(512, 2)
void conv_min_mfma5(const unsigned short* __restrict__ xt,
                    const unsigned short* __restrict__ wt,
                    const float* __restrict__ bias,
                    float* __restrict__ out) {
  __shared__ __align__(16) unsigned short sX[3][4][130][32];   // 99840 B
  __shared__ __align__(16) unsigned short sW[2][3][128][32];   // 49152 B
  __shared__ float sRed[2][512];                               //  4096 B

  const int t   = threadIdx.x;
  const int bid = blockIdx.x;
  const int swz = (bid & 7) * 128 + (bid >> 3);   // 1024 = 8*128, bijective
  const int n   = swz >> 5;
  const int oh0 = (swz & 31) * 4;

  const int lane = t & 63, w = t >> 6;
  const int wc = w & 1, wp = w >> 1;              // co-half, px-row
  const int lg = lane >> 4, ln = lane & 15;

  // staging lane offsets (r-invariant)
  const int xcq   = (t >> 2) * 64 + (t & 3) * 8;          // c = t>>2, q4 = t&3
  const int wco_o = (t >> 2) * 576 + (t & 3) * 8;         // co = t>>2

  // fragment read bases (swizzle chunk is mi/ni-invariant)
  const int chA = lg ^ ((ln >> 1) & 3);
  const char* Abase = (const char*)&sW[0][0][0][0] +
                      ((wc * 64 + ln) * 64 + chA * 16);   // + wb2*24576 + kw*8192 + mi*1024
  const char* Bbase[3];
  #pragma unroll
  for (int kw = 0; kw < 3; ++kw) {
    int chB = lg ^ (((ln + kw) >> 1) & 3);
    Bbase[kw] = (const char*)&sX[0][0][0][0] +
                (wp * 8320 + (ln + kw) * 64 + chB * 16);  // + xb*33280 + ni*1024
  }

  f32x4 acc[4][8];
  #pragma unroll
  for (int i = 0; i < 4; ++i)
    #pragma unroll
    for (int j = 0; j < 8; ++j)
      acc[i][j] = (f32x4){0.f, 0.f, 0.f, 0.f};

  auto stageX = [&](int g) {            // writes sX[g%3], rows (kh=g>>1, half=g&1)
    const int kh = g >> 1, half = g & 1;
    unsigned short* ldsX = &sX[g % 3][0][0][0];
    #pragma unroll
    for (int r = 0; r < 4; ++r) {
      int h = oh0 + kh + r;
      h = h > 127 ? 127 : h;            // tail clamp (store-masked rows only)
      gload_lds16(xt + ((size_t)(n * 128 + h) << 13) + half * 32 + xcq,
                  ldsX + r * 4160 + w * 512);
    }
  };
  auto stageW = [&](int g) {            // writes sW[g%2], slice (kh, half)
    const int kh = g >> 1, half = g & 1;
    unsigned short* ldsW = &sW[g % 2][0][0][0];
    const int wb = kh * 64 + half * 32;
    #pragma unroll
    for (int r = 0; r < 3; ++r)
      gload_lds16(wt + wb + wco_o + r * 192, ldsW + r * 4096 + w * 512);
  };

  // prologue: prime W(0), X(0), X(1); retire W(0)+X(0) (7 oldest), keep X(1) in flight
  stageW(0);
  stageX(0);
  stageX(1);
  asm volatile("s_waitcnt vmcnt(4)" ::: "memory");
  __builtin_amdgcn_s_barrier();

  #pragma unroll
  for (int g = 0; g < 6; ++g) {
    const int xb = g % 3, wb2 = g & 1;
    #pragma unroll
    for (int kw = 0; kw < 3; ++kw) {
      // ---- phase: read fragments for (g, kw) ----
      bf16x8 af[4], bfr[8];
      const char* bA = Abase + wb2 * 24576 + kw * 8192;
      const char* bB = Bbase[kw] + xb * 33280;
      #pragma unroll
      for (int mi = 0; mi < 4; ++mi)
        af[mi] = *(const bf16x8*)(bA + mi * 1024);
      #pragma unroll
      for (int ni = 0; ni < 8; ++ni)
        bfr[ni] = *(const bf16x8*)(bB + ni * 1024);

      if (kw == 0) {                    // issue next stages (W older than X for vmcnt)
        if (g <= 4) stageW(g + 1);
        if (g <= 3) stageX(g + 2);
      }
      if (kw == 2) {                    // group-boundary wait: next group's buffers
        if (g <= 3)      asm volatile("s_waitcnt vmcnt(4)" ::: "memory");
        else if (g == 4) asm volatile("s_waitcnt vmcnt(0)" ::: "memory");
      }

      __builtin_amdgcn_s_barrier();
      asm volatile("s_waitcnt lgkmcnt(0)" ::: "memory");
      __builtin_amdgcn_sched_barrier(0);
      __builtin_amdgcn_s_setprio(1);
      #pragma unroll
      for (int mi = 0; mi < 4; ++mi)
        #pragma unroll
        for (int ni = 0; ni < 8; ++ni)
          acc[mi][ni] = __builtin_amdgcn_mfma_f32_16x16x32_bf16(
              af[mi], bfr[ni], acc[mi][ni], 0, 0, 0);
      __builtin_amdgcn_s_setprio(0);
      __builtin_amdgcn_s_barrier();
      if (kw == 2)                      // pin: next group's reads stay below
        __builtin_amdgcn_sched_barrier(0);
    }
  }

  // epilogue: (acc + bias)*0.5, min over co
  // C/D: col = ln = px within ni-frag, row = lg*4 + r = co within mi-frag
  float bv[4][4];
  #pragma unroll
  for (int mi = 0; mi < 4; ++mi)
    #pragma unroll
    for (int r = 0; r < 4; ++r)
      bv[mi][r] = bias[wc * 64 + mi * 16 + lg * 4 + r];

  #pragma unroll
  for (int ni = 0; ni < 8; ++ni) {
    float m = 3.4e38f;
    #pragma unroll
    for (int mi = 0; mi < 4; ++mi)
      #pragma unroll
      for (int r = 0; r < 4; ++r)
        m = fminf(m, (acc[mi][ni][r] + bv[mi][r]) * 0.5f);
    m = fminf(m, __shfl_xor(m, 16));
    m = fminf(m, __shfl_xor(m, 32));
    if (lg == 0) sRed[wc][wp * 128 + ni * 16 + ln] = m;
  }
  __syncthreads();
  {
    int row = t >> 7, c = t & 127;
    if (c < OWw && oh0 + row < OHh)
      out[((size_t)n * OHh + oh0 + row) * OWw + c] = fminf(sRed[0][t], sRed[1][t]);
  }
}

// ================= fallbacks (round-1 path, used only if ws too small) ==============
__global__ void prep_wt_kernel(const float* __restrict__ w,
                               unsigned short* __restrict__ wt) {
  int i = blockIdx.x * 256 + threadIdx.x;
  if (i >= COUT * KTOT) return;
  int co = i / KTOT, kp = i - co * KTOT;
  int kw = kp / 192, rem = kp - kw * 192;
  int ci = rem / 3, kh = rem - ci * 3;
  wt[i] = f2bf(w[co * 576 + ci * 9 + kh * 3 + kw]);
}

template <bool USE_WT>
__global__ __launch_bounds__(256, 2)
void conv_min_fb(const float* __restrict__ x, const float* __restrict__ w,
                 const float* __restrict__ bias, const unsigned short* __restrict__ wt,
                 float* __restrict__ out) {
  __shared__ __align__(16) unsigned short sW[128][40];
  __shared__ __align__(16) unsigned short sX[128][40];
  __shared__ float sBias[COUT];
  __shared__ float sRed[2][128];
  const int t = threadIdx.x, bid = blockIdx.x;
  const int n = bid / OHh, oh = bid - n * OHh;
  if (t < COUT) sBias[t] = bias[t];
  const int hq = t & 7, q = t >> 3, c0 = q * 4;
  const int wco = t >> 1, whalf = t & 1;
  const int lane = t & 63, lg = lane >> 4, ln = lane & 15;
  const int wv = t >> 6, wc = wv & 1, wp = wv >> 1;
  f32x4 acc[4][4];
  #pragma unroll
  for (int i = 0; i < 4; ++i)
    #pragma unroll
    for (int j = 0; j < 4; ++j) acc[i][j] = (f32x4){0.f, 0.f, 0.f, 0.f};
  const float* xn = x + (size_t)n * CIN * CH * CW;
  for (int s = 0; s < 18; ++s) {
    const int k0 = s * 32;
    const int kw_s = s / 6;
    const int rembase = (s - kw_s * 6) * 32;
    float4 xa[2], xb[2]; int kkp[2];
    #pragma unroll
    for (int pi = 0; pi < 2; ++pi) {
      const int kk = 2 * hq + 16 * pi; kkp[pi] = kk;
      int rem0 = rembase + kk, ci0 = rem0 / 3, kh0 = rem0 - ci0 * 3;
      int rem1 = rem0 + 1, ci1 = rem1 / 3, kh1 = rem1 - ci1 * 3;
      xa[pi] = *(const float4*)(xn + (ci0 * CH + (oh + kh0)) * CW + c0);
      xb[pi] = *(const float4*)(xn + (ci1 * CH + (oh + kh1)) * CW + c0);
    }
    uint4 wv0, wv1;
    if constexpr (USE_WT) {
      const uint4* src = (const uint4*)(wt + wco * KTOT + k0 + whalf * 16);
      wv0 = src[0]; wv1 = src[1];
    } else {
      unsigned tmp[8];
      #pragma unroll
      for (int e = 0; e < 8; ++e) {
        int kk = whalf * 16 + 2 * e;
        int rem0 = rembase + kk, ci0 = rem0 / 3, kh0 = rem0 - ci0 * 3;
        int rem1 = rem0 + 1, ci1 = rem1 / 3, kh1 = rem1 - ci1 * 3;
        tmp[e] = (unsigned)f2bf(w[wco * 576 + ci0 * 9 + kh0 * 3 + kw_s]) |
                 ((unsigned)f2bf(w[wco * 576 + ci1 * 9 + kh1 * 3 + kw_s]) << 16);
      }
      wv0 = make_uint4(tmp[0], tmp[1], tmp[2], tmp[3]);
      wv1 = make_uint4(tmp[4], tmp[5], tmp[6], tmp[7]);
    }
    __syncthreads();
    #pragma unroll
    for (int pi = 0; pi < 2; ++pi)
      #pragma unroll
      for (int j = 0; j < 4; ++j) {
        int p = c0 + j - kw_s;
        unsigned pk = (unsigned)f2bf(((const float*)&xa[pi])[j]) |
                      ((unsigned)f2bf(((const float*)&xb[pi])[j]) << 16);
        if (p >= 0) *(unsigned*)&sX[p][kkp[pi]] = pk;
      }
    *(uint4*)&sW[wco][whalf * 16] = wv0;
    *(uint4*)&sW[wco][whalf * 16 + 8] = wv1;
    __syncthreads();
    bf16x8 af[4], bfr[4];
    #pragma unroll
    for (int mi = 0; mi < 4; ++mi) af[mi] = *(const bf16x8*)&sW[wc * 64 + mi * 16 + ln][lg * 8];
    #pragma unroll
    for (int ni = 0; ni < 4; ++ni) bfr[ni] = *(const bf16x8*)&sX[wp * 64 + ni * 16 + ln][lg * 8];
    #pragma unroll
    for (int mi = 0; mi < 4; ++mi)
      #pragma unroll
      for (int ni = 0; ni < 4; ++ni)
        acc[mi][ni] = __builtin_amdgcn_mfma_f32_16x16x32_bf16(af[mi], bfr[ni], acc[mi][ni], 0, 0, 0);
  }
  #pragma unroll
  for (int ni = 0; ni < 4; ++ni) {
    float m = 3.4e38f;
    #pragma unroll
    for (int mi = 0; mi < 4; ++mi)
      #pragma unroll
      for (int r = 0; r < 4; ++r)
        m = fminf(m, (acc[mi][ni][r] + sBias[wc * 64 + mi * 16 + lg * 4 + r]) * 0.5f);
    m = fminf(m, __shfl_xor(m, 16));
    m = fminf(m, __shfl_xor(m, 32));
    if (lg == 0) sRed[wc][wp * 64 + ni * 16 + ln] = m;
  }
  __syncthreads();
  if (t < OWw) out[(size_t)(n * OHh + oh) * OWw + t] = fminf(sRed[0][t], sRed[1][t]);
}

extern "C" void kernel_launch(void* const* d_in, const int* in_sizes, int n_in,
                              void* d_out, int out_size, void* d_ws, size_t ws_size,
                              hipStream_t stream) {
  const float* x    = (const float*)d_in[0];
  const float* w    = (const float*)d_in[1];
  const float* bias = (const float*)d_in[2];
  float* out = (float*)d_out;

  const size_t XT_BYTES = (size_t)CN * CH * CW * CIN * 2;  // 67,108,864
  const size_t WT_BYTES = (size_t)COUT * KTOT * 2;         // 147,456

  if (d_ws && ws_size >= XT_BYTES + WT_BYTES) {
    unsigned short* xt = (unsigned short*)d_ws;
    unsigned short* wt = (unsigned short*)((char*)d_ws + XT_BYTES);
    prep_xt_kernel<<<CN * CH, 256, 0, stream>>>(x, xt);
    prep_wt2_kernel<<<(COUT * KTOT + 255) / 256, 256, 0, stream>>>(w, wt);
    conv_min_mfma5<<<1024, 512, 0, stream>>>(xt, wt, bias, out);
  } else if (d_ws && ws_size >= WT_BYTES) {
    unsigned short* wt = (unsigned short*)d_ws;
    prep_wt_kernel<<<(COUT * KTOT + 255) / 256, 256, 0, stream>>>(w, wt);
    conv_min_fb<true><<<CN * OHh, 256, 0, stream>>>(x, w, bias, wt, out);
  } else {
    conv_min_fb<false><<<CN * OHh, 256, 0, stream>>>(x, w, bias, nullptr, out);
  }
}

// Round 5
// 104.087 us; speedup vs baseline: 1.0698x; 1.0698x over previous
//
#include <hip/hip_runtime.h>

constexpr int CN   = 32;
constexpr int CIN  = 64;
constexpr int CH   = 128;
constexpr int CW   = 128;
constexpr int COUT = 128;
constexpr int OHh  = 126;
constexpr int OWw  = 126;
constexpr int KTOT = 576;

typedef __attribute__((ext_vector_type(8))) short bf16x8;
typedef __attribute__((ext_vector_type(4))) float f32x4;

__device__ __forceinline__ unsigned short f2bf(float f) {
  union { float f; unsigned u; } v; v.f = f;
  unsigned u = v.u;
  u += 0x7FFFu + ((u >> 16) & 1u);   // RNE
  return (unsigned short)(u >> 16);
}

__device__ __forceinline__ void gload_lds16(const unsigned short* g, unsigned short* l) {
  __builtin_amdgcn_global_load_lds(
      (const __attribute__((address_space(1))) unsigned int*)g,
      (__attribute__((address_space(3))) unsigned int*)l, 16, 0, 0);
}

// ---- prep: x (N,Ci,H,W) fp32 -> xt[n][h][c][ci] bf16, T2 swizzle baked --------------
// Within each 32-ci half, logical octet o stored at slot o ^ ((c>>1)&3).
__global__ __launch_bounds__(256) void prep_xt_kernel(const float* __restrict__ x,
                                                      unsigned short* __restrict__ xt) {
  __shared__ __align__(16) unsigned short s[128][72];
  const int b = blockIdx.x;            // n*128 + h
  const int n = b >> 7, h = b & 127;
  const float* src = x + (size_t)n * CIN * CH * CW + (size_t)h * CW;
  const int t = threadIdx.x;
  #pragma unroll
  for (int r = 0; r < 8; ++r) {
    int idx = r * 256 + t;
    int ci = idx >> 5, c0 = (idx & 31) << 2;
    float4 v = *(const float4*)(src + (size_t)ci * (CH * CW) + c0);
    s[c0 + 0][ci] = f2bf(v.x);
    s[c0 + 1][ci] = f2bf(v.y);
    s[c0 + 2][ci] = f2bf(v.z);
    s[c0 + 3][ci] = f2bf(v.w);
  }
  __syncthreads();
  unsigned short* dst = xt + (size_t)b * 8192;
  #pragma unroll
  for (int r = 0; r < 4; ++r) {
    int idx = r * 256 + t;
    int c = idx >> 3, sl = idx & 7;
    int half = sl >> 2, q = sl & 3;
    int lo = q ^ ((c >> 1) & 3);
    uint4 v = *(const uint4*)&s[c][half * 32 + lo * 8];
    *(uint4*)(dst + (size_t)c * 64 + sl * 8) = v;
  }
}

// ---- prep: W -> wt3, A-fragment-ordered: [p:18][wc:2][mi:4][lane:64][j:8] -----------
// p = G*3+kw, G = kh*2+half; co = wc*64+mi*16+(lane&15); ci = half*32+(lane>>4)*8+j.
__global__ void prep_wt3_kernel(const float* __restrict__ w,
                                unsigned short* __restrict__ wt3) {
  int e = blockIdx.x * 256 + threadIdx.x;
  if (e >= COUT * KTOT) return;
  int j = e & 7, lane = (e >> 3) & 63, mi = (e >> 9) & 3, wc = (e >> 11) & 1;
  int p = e >> 12;                 // 0..17
  int G = p / 3, kw = p - G * 3;
  int kh = G >> 1, half = G & 1;
  int co = wc * 64 + mi * 16 + (lane & 15);
  int ci = half * 32 + (lane >> 4) * 8 + j;
  wt3[e] = f2bf(w[co * 576 + ci * 9 + kh * 3 + kw]);
}

// ---- main: 512 thr, 8 waves (wc2 x wr2 x wh2), M=128 x N=256 (2 rows), 2 blk/CU -----
__global__ __launch_bounds__(512, 4)
void conv_min_mfma6(const unsigned short* __restrict__ xt,
                    const unsigned short* __restrict__ wt3,
                    const float* __restrict__ bias,
                    float* __restrict__ out) {
  __shared__ __align__(16) unsigned short sX[2][2][130][32];   // 33280 B
  __shared__ float sRed[2][256];                               //  2048 B

  const int t   = threadIdx.x;
  const int bid = blockIdx.x;
  const int swz = (bid & 7) * 252 + (bid >> 3);   // 2016 = 8*252, bijective
  const int n   = swz / 63;
  const int oh0 = (swz - n * 63) * 2;

  const int lane = t & 63, w = t >> 6;
  const int wc = w & 1;              // co half
  const int wr = (w >> 1) & 1;       // output row within block
  const int wh = w >> 2;             // pixel 64-half
  const int lg = lane >> 4, ln = lane & 15;

  const int xcq = (t >> 2) * 64 + (t & 3) * 8;    // X staging: c = t>>2, q4 = t&3

  // B fragment byte-bases into sX (chunk swizzle is ni-invariant)
  const char* Bb[3];
  #pragma unroll
  for (int kw = 0; kw < 3; ++kw) {
    int row = wh * 64 + ln + kw;                  // <=129
    int ch = lg ^ ((row >> 1) & 3);
    Bb[kw] = (const char*)&sX[0][0][0][0] + wr * 8320 + row * 64 + ch * 16;
  }
  // A fragment lane base (global, contiguous per wave per phase)
  const unsigned short* wlane = wt3 + wc * 2048 + lane * 8;   // + p*4096 + mi*512

  f32x4 acc[4][4];
  #pragma unroll
  for (int i = 0; i < 4; ++i)
    #pragma unroll
    for (int j = 0; j < 4; ++j)
      acc[i][j] = (f32x4){0.f, 0.f, 0.f, 0.f};

  auto stageX = [&](int G, int buf) {             // 2 gload_lds per thread
    #pragma unroll
    for (int r = 0; r < 2; ++r) {
      int h = oh0 + (G >> 1) + r;                 // <=127 always (oh0<=124)
      gload_lds16(xt + ((size_t)(n * 128 + h) << 13) + (G & 1) * 32 + xcq,
                  &sX[buf][r][0][0] + w * 512);
    }
  };

  stageX(0, 0);

  #pragma unroll
  for (int p = 0; p < 18; ++p) {
    const int G = p / 3, kw = p - G * 3, buf = G & 1;
    if (kw == 0) {
      asm volatile("s_waitcnt vmcnt(0)" ::: "memory");   // X(G) landed (per-wave)
      __builtin_amdgcn_s_barrier();                      // all waves: X(G) ready,
      if (G < 5) stageX(G + 1, buf ^ 1);                 // prev buf reads done
    }
    bf16x8 af[4], bfr[4];
    #pragma unroll
    for (int mi = 0; mi < 4; ++mi)
      af[mi] = *(const bf16x8*)(wlane + p * 4096 + mi * 512);
    #pragma unroll
    for (int ni = 0; ni < 4; ++ni)
      bfr[ni] = *(const bf16x8*)(Bb[kw] + buf * 16640 + ni * 1024);
    __builtin_amdgcn_s_setprio(1);
    #pragma unroll
    for (int mi = 0; mi < 4; ++mi)
      #pragma unroll
      for (int ni = 0; ni < 4; ++ni)
        acc[mi][ni] = __builtin_amdgcn_mfma_f32_16x16x32_bf16(
            af[mi], bfr[ni], acc[mi][ni], 0, 0, 0);
    __builtin_amdgcn_s_setprio(0);
  }

  // epilogue: (acc + bias)*0.5, min over co
  // C/D: col = ln = px within ni-frag, row = lg*4 + r = co within mi-frag
  float bv[4][4];
  #pragma unroll
  for (int mi = 0; mi < 4; ++mi)
    #pragma unroll
    for (int r = 0; r < 4; ++r)
      bv[mi][r] = bias[wc * 64 + mi * 16 + lg * 4 + r];

  #pragma unroll
  for (int ni = 0; ni < 4; ++ni) {
    float m = 3.4e38f;
    #pragma unroll
    for (int mi = 0; mi < 4; ++mi)
      #pragma unroll
      for (int r = 0; r < 4; ++r)
        m = fminf(m, (acc[mi][ni][r] + bv[mi][r]) * 0.5f);
    m = fminf(m, __shfl_xor(m, 16));
    m = fminf(m, __shfl_xor(m, 32));
    if (lg == 0) sRed[wc][wr * 128 + wh * 64 + ni * 16 + ln] = m;
  }
  __syncthreads();
  if (t < 256) {
    int row = t >> 7, c = t & 127;
    if (c < OWw)
      out[((size_t)n * OHh + oh0 + row) * OWw + c] = fminf(sRed[0][t], sRed[1][t]);
  }
}

// ================= fallbacks (round-1 path, used only if ws too small) ==============
__global__ void prep_wt_kernel(const float* __restrict__ w,
                               unsigned short* __restrict__ wt) {
  int i = blockIdx.x * 256 + threadIdx.x;
  if (i >= COUT * KTOT) return;
  int co = i / KTOT, kp = i - co * KTOT;
  int kw = kp / 192, rem = kp - kw * 192;
  int ci = rem / 3, kh = rem - ci * 3;
  wt[i] = f2bf(w[co * 576 + ci * 9 + kh * 3 + kw]);
}

template <bool USE_WT>
__global__ __launch_bounds__(256, 2)
void conv_min_fb(const float* __restrict__ x, const float* __restrict__ w,
                 const float* __restrict__ bias, const unsigned short* __restrict__ wt,
                 float* __restrict__ out) {
  __shared__ __align__(16) unsigned short sW[128][40];
  __shared__ __align__(16) unsigned short sX[128][40];
  __shared__ float sBias[COUT];
  __shared__ float sRed[2][128];
  const int t = threadIdx.x, bid = blockIdx.x;
  const int n = bid / OHh, oh = bid - n * OHh;
  if (t < COUT) sBias[t] = bias[t];
  const int hq = t & 7, q = t >> 3, c0 = q * 4;
  const int wco = t >> 1, whalf = t & 1;
  const int lane = t & 63, lg = lane >> 4, ln = lane & 15;
  const int wv = t >> 6, wc = wv & 1, wp = wv >> 1;
  f32x4 acc[4][4];
  #pragma unroll
  for (int i = 0; i < 4; ++i)
    #pragma unroll
    for (int j = 0; j < 4; ++j) acc[i][j] = (f32x4){0.f, 0.f, 0.f, 0.f};
  const float* xn = x + (size_t)n * CIN * CH * CW;
  for (int s = 0; s < 18; ++s) {
    const int k0 = s * 32;
    const int kw_s = s / 6;
    const int rembase = (s - kw_s * 6) * 32;
    float4 xa[2], xb[2]; int kkp[2];
    #pragma unroll
    for (int pi = 0; pi < 2; ++pi) {
      const int kk = 2 * hq + 16 * pi; kkp[pi] = kk;
      int rem0 = rembase + kk, ci0 = rem0 / 3, kh0 = rem0 - ci0 * 3;
      int rem1 = rem0 + 1, ci1 = rem1 / 3, kh1 = rem1 - ci1 * 3;
      xa[pi] = *(const float4*)(xn + (ci0 * CH + (oh + kh0)) * CW + c0);
      xb[pi] = *(const float4*)(xn + (ci1 * CH + (oh + kh1)) * CW + c0);
    }
    uint4 wv0, wv1;
    if constexpr (USE_WT) {
      const uint4* src = (const uint4*)(wt + wco * KTOT + k0 + whalf * 16);
      wv0 = src[0]; wv1 = src[1];
    } else {
      unsigned tmp[8];
      #pragma unroll
      for (int e = 0; e < 8; ++e) {
        int kk = whalf * 16 + 2 * e;
        int rem0 = rembase + kk, ci0 = rem0 / 3, kh0 = rem0 - ci0 * 3;
        int rem1 = rem0 + 1, ci1 = rem1 / 3, kh1 = rem1 - ci1 * 3;
        tmp[e] = (unsigned)f2bf(w[wco * 576 + ci0 * 9 + kh0 * 3 + kw_s]) |
                 ((unsigned)f2bf(w[wco * 576 + ci1 * 9 + kh1 * 3 + kw_s]) << 16);
      }
      wv0 = make_uint4(tmp[0], tmp[1], tmp[2], tmp[3]);
      wv1 = make_uint4(tmp[4], tmp[5], tmp[6], tmp[7]);
    }
    __syncthreads();
    #pragma unroll
    for (int pi = 0; pi < 2; ++pi)
      #pragma unroll
      for (int j = 0; j < 4; ++j) {
        int p = c0 + j - kw_s;
        unsigned pk = (unsigned)f2bf(((const float*)&xa[pi])[j]) |
                      ((unsigned)f2bf(((const float*)&xb[pi])[j]) << 16);
        if (p >= 0) *(unsigned*)&sX[p][kkp[pi]] = pk;
      }
    *(uint4*)&sW[wco][whalf * 16] = wv0;
    *(uint4*)&sW[wco][whalf * 16 + 8] = wv1;
    __syncthreads();
    bf16x8 af[4], bfr[4];
    #pragma unroll
    for (int mi = 0; mi < 4; ++mi) af[mi] = *(const bf16x8*)&sW[wc * 64 + mi * 16 + ln][lg * 8];
    #pragma unroll
    for (int ni = 0; ni < 4; ++ni) bfr[ni] = *(const bf16x8*)&sX[wp * 64 + ni * 16 + ln][lg * 8];
    #pragma unroll
    for (int mi = 0; mi < 4; ++mi)
      #pragma unroll
      for (int ni = 0; ni < 4; ++ni)
        acc[mi][ni] = __builtin_amdgcn_mfma_f32_16x16x32_bf16(af[mi], bfr[ni], acc[mi][ni], 0, 0, 0);
  }
  #pragma unroll
  for (int ni = 0; ni < 4; ++ni) {
    float m = 3.4e38f;
    #pragma unroll
    for (int mi = 0; mi < 4; ++mi)
      #pragma unroll
      for (int r = 0; r < 4; ++r)
        m = fminf(m, (acc[mi][ni][r] + sBias[wc * 64 + mi * 16 + lg * 4 + r]) * 0.5f);
    m = fminf(m, __shfl_xor(m, 16));
    m = fminf(m, __shfl_xor(m, 32));
    if (lg == 0) sRed[wc][wp * 64 + ni * 16 + ln] = m;
  }
  __syncthreads();
  if (t < OWw) out[(size_t)(n * OHh + oh) * OWw + t] = fminf(sRed[0][t], sRed[1][t]);
}

extern "C" void kernel_launch(void* const* d_in, const int* in_sizes, int n_in,
                              void* d_out, int out_size, void* d_ws, size_t ws_size,
                              hipStream_t stream) {
  const float* x    = (const float*)d_in[0];
  const float* w    = (const float*)d_in[1];
  const float* bias = (const float*)d_in[2];
  float* out = (float*)d_out;

  const size_t XT_BYTES = (size_t)CN * CH * CW * CIN * 2;  // 67,108,864
  const size_t WT_BYTES = (size_t)COUT * KTOT * 2;         // 147,456

  if (d_ws && ws_size >= XT_BYTES + WT_BYTES) {
    unsigned short* xt  = (unsigned short*)d_ws;
    unsigned short* wt3 = (unsigned short*)((char*)d_ws + XT_BYTES);
    prep_xt_kernel<<<CN * CH, 256, 0, stream>>>(x, xt);
    prep_wt3_kernel<<<(COUT * KTOT + 255) / 256, 256, 0, stream>>>(w, wt3);
    conv_min_mfma6<<<2016, 512, 0, stream>>>(xt, wt3, bias, out);
  } else if (d_ws && ws_size >= WT_BYTES) {
    unsigned short* wt = (unsigned short*)d_ws;
    prep_wt_kernel<<<(COUT * KTOT + 255) / 256, 256, 0, stream>>>(w, wt);
    conv_min_fb<true><<<CN * OHh, 256, 0, stream>>>(x, w, bias, wt, out);
  } else {
    conv_min_fb<false><<<CN * OHh, 256, 0, stream>>>(x, w, bias, nullptr, out);
  }
}

// Round 6
// 88.435 us; speedup vs baseline: 1.2592x; 1.1770x over previous
//
#include <hip/hip_runtime.h>
#include <hip/hip_bf16.h>

constexpr int CN   = 32;
constexpr int CIN  = 64;
constexpr int CH   = 128;
constexpr int CW   = 128;
constexpr int COUT = 128;
constexpr int OHh  = 126;
constexpr int OWw  = 126;
constexpr int KTOT = 576;

typedef __attribute__((ext_vector_type(8))) short bf16x8;
typedef __attribute__((ext_vector_type(4))) float f32x4;

__device__ __forceinline__ unsigned short f2bf(float f) {
  union { float f; unsigned u; } v; v.f = f;
  unsigned u = v.u;
  u += 0x7FFFu + ((u >> 16) & 1u);   // RNE
  return (unsigned short)(u >> 16);
}

__device__ __forceinline__ unsigned packbf2(float a, float b) {
  union { __hip_bfloat162 h; unsigned u; } v;
  v.h = __float22bfloat162_rn(make_float2(a, b));   // compiler emits v_cvt_pk_bf16_f32
  return v.u;
}

// ---- prep: W -> wt3, A-fragment-ordered: [p:18][wc:2][mi:4][lane:64][j:8] -----------
// p = G*3+kw, G = kh*2+half; co = wc*64+mi*16+(lane&15); ci = half*32+(lane>>4)*8+j.
__global__ void prep_wt3_kernel(const float* __restrict__ w,
                                unsigned short* __restrict__ wt3) {
  int e = blockIdx.x * 256 + threadIdx.x;
  if (e >= COUT * KTOT) return;
  int j = e & 7, lane = (e >> 3) & 63, mi = (e >> 9) & 3, wc = (e >> 11) & 1;
  int p = e >> 12;                 // 0..17
  int G = p / 3, kw = p - G * 3;
  int kh = G >> 1, half = G & 1;
  int co = wc * 64 + mi * 16 + (lane & 15);
  int ci = half * 32 + (lane >> 4) * 8 + j;
  wt3[e] = f2bf(w[co * 576 + ci * 9 + kh * 3 + kw]);
}

// ---- main: 512 thr, 8 waves (wc2 x wr2 x wh2), M=128 x N=256 (2 rows), 2 blk/CU -----
// x read directly (fp32), converted+transposed in-register, ds_write_b128 staged.
__global__ __launch_bounds__(512, 4)
void conv_min_mfma7(const float* __restrict__ x,
                    const unsigned short* __restrict__ wt3,
                    const float* __restrict__ bias,
                    float* __restrict__ out) {
  __shared__ __align__(16) unsigned short sX[2][2][130][32];   // [buf][r][c(pad)][ci-half] 33280 B
  __shared__ float sRed[2][256];                               //  2048 B

  const int t   = threadIdx.x;
  const int bid = blockIdx.x;
  const int swz = (bid & 7) * 252 + (bid >> 3);   // 2016 = 8*252, bijective
  const int n   = swz / 63;
  const int oh0 = (swz - n * 63) * 2;             // <=124

  const int lane = t & 63, w = t >> 6;
  const int wc = w & 1;              // co half
  const int wr = (w >> 1) & 1;       // output row within block
  const int wh = w >> 2;             // pixel 64-half
  const int lg = lane >> 4, ln = lane & 15;

  // staging roles: row sr, octet so, column sc (cells c=sc and c=sc+64)
  const int sr = t >> 8;
  const int so = (t >> 6) & 3;
  const int sc = t & 63;

  // B fragment byte-bases into sX (chunk swizzle is ni-invariant)
  const char* Bb[3];
  #pragma unroll
  for (int kw = 0; kw < 3; ++kw) {
    int row = wh * 64 + ln + kw;                  // <=129 (pad rows: finite garbage only)
    int ch = lg ^ ((row >> 1) & 3);
    Bb[kw] = (const char*)&sX[0][0][0][0] + wr * 8320 + row * 64 + ch * 16;
  }
  // A fragment lane base (global, contiguous per wave per phase, L1/L2-resident)
  const unsigned short* wlane = wt3 + wc * 2048 + lane * 8;   // + p*4096 + mi*512

  f32x4 acc[4][4];
  #pragma unroll
  for (int i = 0; i < 4; ++i)
    #pragma unroll
    for (int j = 0; j < 4; ++j)
      acc[i][j] = (f32x4){0.f, 0.f, 0.f, 0.f};

  float svA[8], svB[8];

  auto stage_load = [&](int G, float (&sv)[8], int e) {
    const int h = oh0 + (G >> 1) + sr;            // <=127
    const size_t base = ((size_t)((n * 64 + (G & 1) * 32 + so * 8) * 128 + h)) * 128
                        + sc + e * 64;
    #pragma unroll
    for (int j = 0; j < 8; ++j)
      sv[j] = x[base + (size_t)j * 16384];        // wave: 64 lanes x 4B contiguous
  };
  auto stage_write = [&](int G, float (&sv)[8], int e) {
    const int c = sc + e * 64;
    const int ch = so ^ ((c >> 1) & 3);           // baked T2 swizzle (matches reads)
    uint4 v = make_uint4(packbf2(sv[0], sv[1]), packbf2(sv[2], sv[3]),
                         packbf2(sv[4], sv[5]), packbf2(sv[6], sv[7]));
    *(uint4*)(&sX[G & 1][sr][c][ch * 8]) = v;     // conflict-free b128 (8 lanes = 32 banks)
  };

  // prologue: stage group 0
  stage_load(0, svA, 0);
  stage_load(0, svB, 1);
  stage_write(0, svA, 0);
  stage_write(0, svB, 1);
  asm volatile("s_waitcnt lgkmcnt(0)" ::: "memory");
  __builtin_amdgcn_s_barrier();
  __builtin_amdgcn_sched_barrier(0);

  #pragma unroll
  for (int p = 0; p < 18; ++p) {
    const int G = p / 3, kw = p - G * 3, buf = G & 1;
    if (kw == 0 && G < 5) {                       // issue-early (T14)
      stage_load(G + 1, svA, 0);
      __builtin_amdgcn_sched_barrier(0);
    }
    bf16x8 af[4], bfr[4];
    #pragma unroll
    for (int mi = 0; mi < 4; ++mi)
      af[mi] = *(const bf16x8*)(wlane + p * 4096 + mi * 512);
    #pragma unroll
    for (int ni = 0; ni < 4; ++ni)
      bfr[ni] = *(const bf16x8*)(Bb[kw] + buf * 16640 + ni * 1024);
    __builtin_amdgcn_s_setprio(1);
    #pragma unroll
    for (int mi = 0; mi < 4; ++mi)
      #pragma unroll
      for (int ni = 0; ni < 4; ++ni)
        acc[mi][ni] = __builtin_amdgcn_mfma_f32_16x16x32_bf16(
            af[mi], bfr[ni], acc[mi][ni], 0, 0, 0);
    __builtin_amdgcn_s_setprio(0);
    if (G < 5) {
      if (kw == 1) {                              // write-late, next cell issue
        stage_write(G + 1, svA, 0);
        stage_load(G + 1, svB, 1);
      }
      if (kw == 2) {
        stage_write(G + 1, svB, 1);
        asm volatile("s_waitcnt lgkmcnt(0)" ::: "memory");
        __builtin_amdgcn_sched_barrier(0);
        __builtin_amdgcn_s_barrier();             // all waves: next buf staged,
        __builtin_amdgcn_sched_barrier(0);        // this buf's reads complete
      }
    }
  }

  // epilogue: (acc + bias)*0.5, min over co
  // C/D: col = ln = px within ni-frag, row = lg*4 + r = co within mi-frag
  float bv[4][4];
  #pragma unroll
  for (int mi = 0; mi < 4; ++mi)
    #pragma unroll
    for (int r = 0; r < 4; ++r)
      bv[mi][r] = bias[wc * 64 + mi * 16 + lg * 4 + r];

  #pragma unroll
  for (int ni = 0; ni < 4; ++ni) {
    float m = 3.4e38f;
    #pragma unroll
    for (int mi = 0; mi < 4; ++mi)
      #pragma unroll
      for (int r = 0; r < 4; ++r)
        m = fminf(m, (acc[mi][ni][r] + bv[mi][r]) * 0.5f);
    m = fminf(m, __shfl_xor(m, 16));
    m = fminf(m, __shfl_xor(m, 32));
    if (lg == 0) sRed[wc][wr * 128 + wh * 64 + ni * 16 + ln] = m;
  }
  __syncthreads();
  if (t < 256) {
    int row = t >> 7, c = t & 127;
    if (c < OWw)
      out[((size_t)n * OHh + oh0 + row) * OWw + c] = fminf(sRed[0][t], sRed[1][t]);
  }
}

// ================= fallback (direct-compute path, used only if ws unusable) =========
__global__ __launch_bounds__(256, 2)
void conv_min_fb(const float* __restrict__ x, const float* __restrict__ w,
                 const float* __restrict__ bias, float* __restrict__ out) {
  __shared__ __align__(16) unsigned short sW[128][40];
  __shared__ __align__(16) unsigned short sX[128][40];
  __shared__ float sBias[COUT];
  __shared__ float sRed[2][128];
  const int t = threadIdx.x, bid = blockIdx.x;
  const int n = bid / OHh, oh = bid - n * OHh;
  if (t < COUT) sBias[t] = bias[t];
  const int hq = t & 7, q = t >> 3, c0 = q * 4;
  const int wco = t >> 1, whalf = t & 1;
  const int lane = t & 63, lg = lane >> 4, ln = lane & 15;
  const int wv = t >> 6, wc = wv & 1, wp = wv >> 1;
  f32x4 acc[4][4];
  #pragma unroll
  for (int i = 0; i < 4; ++i)
    #pragma unroll
    for (int j = 0; j < 4; ++j) acc[i][j] = (f32x4){0.f, 0.f, 0.f, 0.f};
  const float* xn = x + (size_t)n * CIN * CH * CW;
  for (int s = 0; s < 18; ++s) {
    const int kw_s = s / 6;
    const int rembase = (s - kw_s * 6) * 32;
    float4 xa[2], xb[2]; int kkp[2];
    #pragma unroll
    for (int pi = 0; pi < 2; ++pi) {
      const int kk = 2 * hq + 16 * pi; kkp[pi] = kk;
      int rem0 = rembase + kk, ci0 = rem0 / 3, kh0 = rem0 - ci0 * 3;
      int rem1 = rem0 + 1, ci1 = rem1 / 3, kh1 = rem1 - ci1 * 3;
      xa[pi] = *(const float4*)(xn + (ci0 * CH + (oh + kh0)) * CW + c0);
      xb[pi] = *(const float4*)(xn + (ci1 * CH + (oh + kh1)) * CW + c0);
    }
    unsigned tmp[8];
    #pragma unroll
    for (int e = 0; e < 8; ++e) {
      int kk = whalf * 16 + 2 * e;
      int rem0 = rembase + kk, ci0 = rem0 / 3, kh0 = rem0 - ci0 * 3;
      int rem1 = rem0 + 1, ci1 = rem1 / 3, kh1 = rem1 - ci1 * 3;
      tmp[e] = (unsigned)f2bf(w[wco * 576 + ci0 * 9 + kh0 * 3 + kw_s]) |
               ((unsigned)f2bf(w[wco * 576 + ci1 * 9 + kh1 * 3 + kw_s]) << 16);
    }
    __syncthreads();
    #pragma unroll
    for (int pi = 0; pi < 2; ++pi)
      #pragma unroll
      for (int j = 0; j < 4; ++j) {
        int p = c0 + j - kw_s;
        unsigned pk = (unsigned)f2bf(((const float*)&xa[pi])[j]) |
                      ((unsigned)f2bf(((const float*)&xb[pi])[j]) << 16);
        if (p >= 0) *(unsigned*)&sX[p][kkp[pi]] = pk;
      }
    *(uint4*)&sW[wco][whalf * 16] = make_uint4(tmp[0], tmp[1], tmp[2], tmp[3]);
    *(uint4*)&sW[wco][whalf * 16 + 8] = make_uint4(tmp[4], tmp[5], tmp[6], tmp[7]);
    __syncthreads();
    bf16x8 af[4], bfr[4];
    #pragma unroll
    for (int mi = 0; mi < 4; ++mi) af[mi] = *(const bf16x8*)&sW[wc * 64 + mi * 16 + ln][lg * 8];
    #pragma unroll
    for (int ni = 0; ni < 4; ++ni) bfr[ni] = *(const bf16x8*)&sX[wp * 64 + ni * 16 + ln][lg * 8];
    #pragma unroll
    for (int mi = 0; mi < 4; ++mi)
      #pragma unroll
      for (int ni = 0; ni < 4; ++ni)
        acc[mi][ni] = __builtin_amdgcn_mfma_f32_16x16x32_bf16(af[mi], bfr[ni], acc[mi][ni], 0, 0, 0);
  }
  #pragma unroll
  for (int ni = 0; ni < 4; ++ni) {
    float m = 3.4e38f;
    #pragma unroll
    for (int mi = 0; mi < 4; ++mi)
      #pragma unroll
      for (int r = 0; r < 4; ++r)
        m = fminf(m, (acc[mi][ni][r] + sBias[wc * 64 + mi * 16 + lg * 4 + r]) * 0.5f);
    m = fminf(m, __shfl_xor(m, 16));
    m = fminf(m, __shfl_xor(m, 32));
    if (lg == 0) sRed[wc][wp * 64 + ni * 16 + ln] = m;
  }
  __syncthreads();
  if (t < OWw) out[(size_t)(n * OHh + oh) * OWw + t] = fminf(sRed[0][t], sRed[1][t]);
}

extern "C" void kernel_launch(void* const* d_in, const int* in_sizes, int n_in,
                              void* d_out, int out_size, void* d_ws, size_t ws_size,
                              hipStream_t stream) {
  const float* x    = (const float*)d_in[0];
  const float* w    = (const float*)d_in[1];
  const float* bias = (const float*)d_in[2];
  float* out = (float*)d_out;

  const size_t WT_BYTES = (size_t)COUT * KTOT * 2;   // 147,456

  if (d_ws && ws_size >= WT_BYTES) {
    unsigned short* wt3 = (unsigned short*)d_ws;
    prep_wt3_kernel<<<(COUT * KTOT + 255) / 256, 256, 0, stream>>>(w, wt3);
    conv_min_mfma7<<<2016, 512, 0, stream>>>(x, wt3, bias, out);
  } else {
    conv_min_fb<<<CN * OHh, 256, 0, stream>>>(x, w, bias, out);
  }
}